// Round 6
// baseline (336.684 us; speedup 1.0000x reference)
//
#include <hip/hip_runtime.h>
#include <math.h>

// SPLoss, FUSED single kernel (round 6 = round-4 structure, compile fix:
// __hip_atomic_fence -> __threadfence; (void)hipMemsetAsync).
// Round-2/3 findings: timed window = 2x 524MB harness poison fills (~152 us
// @ 87% HBM write roofline) + CE (~45 us: 131 MB read competing with L3
// fill-drain) + K2 (~10 us) + gaps. CE speed is set by drain competition
// (structure-invariant across 2 sessions); the compressible part is the
// K2 launch boundary + its phase-A ceu re-read. So: fuse.
//  - 1024 blocks x 256 thr, grid-stride CE, 8 rows/wave @ B=32768.
//  - each wave histograms its OWN ce values into LDS (no ceu re-read),
//    block merges -> atomicAdd into 16 ghist slices (blockIdx&15: 64
//    staggered sources/slice; keeps round-7 anti-contention structure).
//  - agent acq_rel ticket; LAST block: sum slices, radix passes 1-3
//    reading ceu from global (131KB x4 ~ 2us; no 128KB LDS stage -> CE
//    phase keeps full occupancy), power reweight + mean.
//  - ghist+ticket zeroed via hipMemsetAsync (block-0 zeroing would race
//    against other blocks' merges inside one kernel).
// ws: [0..B) uint ce bits, [B..B+16*256) slice hists, [B+4096] ticket.

__device__ __forceinline__ unsigned f2u(float f) {
    unsigned u = __float_as_uint(f);
    return (u & 0x80000000u) ? ~u : (u | 0x80000000u);
}
__device__ __forceinline__ float u2f(unsigned u) {
    unsigned b = (u & 0x80000000u) ? (u & 0x7FFFFFFFu) : ~u;
    return __uint_as_float(b);
}

#define CE_BLOCKS 1024
#define CE_T      256
#define CE_W      4            // waves per block
#define NSLICE    16

__global__ __launch_bounds__(CE_T) void sploss_fused(
        const float* __restrict__ x, const int* __restrict__ tgt,
        const int* __restrict__ epoch_p, float* __restrict__ out,
        unsigned* __restrict__ ceu, unsigned* __restrict__ ghist,
        int B, int C)
{
    __shared__ unsigned wh[CE_W][256];    // 4 KB per-wave pass-0 hists
    __shared__ unsigned sh[256];
    __shared__ unsigned s_prefix, s_k, s_old;
    __shared__ float    s_wsum[CE_W];

    const int tid  = threadIdx.x;
    const int lane = tid & 63;
    const int wave = tid >> 6;
    unsigned* ticket = ghist + NSLICE * 256;

    // ---- zero per-wave hists ----
    #pragma unroll
    for (int j = 0; j < 4; ++j) ((unsigned*)wh)[tid * 4 + j] = 0u;
    __syncthreads();

    // ---- CE phase: grid-stride, 1 wave/row, register slice ----
    const int wstride = CE_BLOCKS * CE_W;              // 4096 waves
    const int C4 = C >> 2;                             // 250 (C%4==0)
    const float NEG = -INFINITY;

    for (int row = blockIdx.x * CE_W + wave; row < B; row += wstride) {
        const float* rp = x + (size_t)row * C;
        const int t = tgt[row];            // dependent pair issued early
        const float tv = rp[t];            // wave-uniform address: 1 transaction

        const float4* p4 = (const float4*)rp;  // row stride 4000 B: 16-B aligned
        float4 v0 = make_float4(NEG, NEG, NEG, NEG), v1 = v0, v2 = v0, v3 = v0;
        if (lane       < C4) v0 = p4[lane];
        if (lane +  64 < C4) v1 = p4[lane + 64];
        if (lane + 128 < C4) v2 = p4[lane + 128];
        if (lane + 192 < C4) v3 = p4[lane + 192];

        float m = fmaxf(fmaxf(fmaxf(v0.x, v0.y), fmaxf(v0.z, v0.w)),
                        fmaxf(fmaxf(v1.x, v1.y), fmaxf(v1.z, v1.w)));
        m = fmaxf(m, fmaxf(fmaxf(v2.x, v2.y), fmaxf(v2.z, v2.w)));
        m = fmaxf(m, fmaxf(fmaxf(v3.x, v3.y), fmaxf(v3.z, v3.w)));
        for (int off = 32; off > 0; off >>= 1)
            m = fmaxf(m, __shfl_xor(m, off, 64));

        float s = __expf(v0.x - m) + __expf(v0.y - m) + __expf(v0.z - m) + __expf(v0.w - m)
                + __expf(v1.x - m) + __expf(v1.y - m) + __expf(v1.z - m) + __expf(v1.w - m)
                + __expf(v2.x - m) + __expf(v2.y - m) + __expf(v2.z - m) + __expf(v2.w - m)
                + __expf(v3.x - m) + __expf(v3.y - m) + __expf(v3.z - m) + __expf(v3.w - m);
        for (int off = 32; off > 0; off >>= 1)
            s += __shfl_xor(s, off, 64);

        if (lane == 0) {
            unsigned cb = f2u((m + __logf(s)) - tv);
            ceu[row] = cb;
            atomicAdd(&wh[wave][cb >> 24], 1u);   // LDS, wave-private hist
        }
    }
    __syncthreads();

    // ---- merge block hist into one of 16 global slices ----
    if (tid < 256) {
        unsigned s = wh[0][tid] + wh[1][tid] + wh[2][tid] + wh[3][tid];
        if (s) atomicAdd(&ghist[(blockIdx.x & (NSLICE - 1)) * 256 + tid], s);
    }
    __syncthreads();                       // merges + ceu stores done

    // ---- ticket: last-arriving block proceeds ----
    if (tid == 0)
        s_old = __hip_atomic_fetch_add(ticket, 1u,
                                       __ATOMIC_ACQ_REL, __HIP_MEMORY_SCOPE_AGENT);
    __syncthreads();
    if (s_old != (unsigned)(gridDim.x - 1)) return;

    // acquire done by the winning RMW; device-scope fence for belt+braces
    __threadfence();
    __syncthreads();

    // ---- tail (1 block, 256 thr): sum slices -> sh ----
    if (tid < 256) {
        unsigned s = 0;
        #pragma unroll
        for (int i = 0; i < NSLICE; ++i)
            s += __hip_atomic_load(&ghist[i * 256 + tid],
                                   __ATOMIC_RELAXED, __HIP_MEMORY_SCOPE_AGENT);
        sh[tid] = s;
    }
    __syncthreads();

    // schedule (mirrors _adjust_N_ratio_q_t; epoch read on-device)
    const int e = epoch_p[0];
    double nr; int qt;
    if (e <= 25)      { nr = 0.7; qt = 2; }
    else if (e <= 75) { nr = 0.8; qt = 0; }
    else if (e <= 95) { nr = 0.9; qt = 0; }
    else              { nr = 1.0; qt = 0; }
    const bool inv = (qt != 2);           // exponent 1/(qt-1) in {+1,-1}

    // ---- pass 0: bucket find from sh (wave 0) ----
    if (wave == 0) {
        long long kk = (long long)((double)B * nr);          // Python int()
        if (kk > (long long)B - 1) kk = (long long)B - 1;    // jnp index clamp
        unsigned c0 = sh[4 * lane],     c1 = sh[4 * lane + 1];
        unsigned c2 = sh[4 * lane + 2], c3 = sh[4 * lane + 3];
        unsigned cw = c0 + c1 + c2 + c3;
        unsigned incl = cw;
        for (int off = 1; off < 64; off <<= 1) {
            unsigned t = __shfl_up(incl, off, 64);
            if (lane >= off) incl += t;
        }
        unsigned excl = incl - cw;
        unsigned kr = (unsigned)kk;
        unsigned long long bm = __ballot(excl <= kr && kr < excl + cw);
        int L = (int)(__ffsll((long long)bm) - 1);
        if (lane == L) {
            unsigned rem = kr - excl;
            int b; unsigned cum;
            if      (rem < c0)           { b = 0; cum = 0; }
            else if (rem < c0 + c1)      { b = 1; cum = c0; }
            else if (rem < c0 + c1 + c2) { b = 2; cum = c0 + c1; }
            else                         { b = 3; cum = c0 + c1 + c2; }
            s_k = rem - cum;
            s_prefix = (unsigned)(4 * L + b) << 24;
        }
    }
    __syncthreads();

    // ---- passes 1-3: scan ceu from global (L2/L3-resident 131 KB) ----
    for (int p = 1; p < 4; ++p) {
        if (tid < 256) sh[tid] = 0u;
        __syncthreads();
        const int shift = 24 - 8 * p;
        const unsigned hm   = 0xFFFFFFFFu << (shift + 8);
        const unsigned pref = s_prefix;
        for (int j = tid; j < B; j += CE_T) {
            unsigned u = ceu[j];
            if ((u & hm) == (pref & hm))
                atomicAdd(&sh[(u >> shift) & 255u], 1u);
        }
        __syncthreads();
        if (wave == 0) {
            unsigned c0 = sh[4 * lane], c1 = sh[4 * lane + 1];
            unsigned c2 = sh[4 * lane + 2], c3 = sh[4 * lane + 3];
            unsigned cw = c0 + c1 + c2 + c3;
            unsigned incl = cw;
            for (int off = 1; off < 64; off <<= 1) {
                unsigned t = __shfl_up(incl, off, 64);
                if (lane >= off) incl += t;
            }
            unsigned excl = incl - cw;
            unsigned kr = s_k;
            unsigned long long bm = __ballot(excl <= kr && kr < excl + cw);
            int L = (int)(__ffsll((long long)bm) - 1);
            if (lane == L) {
                unsigned rem = kr - excl;
                int b; unsigned cum;
                if      (rem < c0)           { b = 0; cum = 0; }
                else if (rem < c0 + c1)      { b = 1; cum = c0; }
                else if (rem < c0 + c1 + c2) { b = 2; cum = c0 + c1; }
                else                         { b = 3; cum = c0 + c1 + c2; }
                s_k = rem - cum;
                s_prefix = pref | ((unsigned)(4 * lane + b) << shift);
            }
        }
        __syncthreads();
    }

    // ---- reweight + mean (global reads, now L2-hot) ----
    const float lam = u2f(s_prefix);      // exact k-th smallest ce
    float part = 0.0f;
    for (int j = tid; j < B; j += CE_T) {
        float c = u2f(ceu[j]);
        float base = 1.0f - c / lam;
        float v = inv ? (1.0f / base) : base;
        if (c >= lam)       v = 0.0f;
        else if (v >= 10.f) v = 10.0f;
        part += c * v;
    }
    for (int off = 32; off > 0; off >>= 1) part += __shfl_xor(part, off, 64);
    if (lane == 0) s_wsum[wave] = part;
    __syncthreads();
    if (tid == 0) {
        float tot = 0.0f;
        for (int i = 0; i < CE_W; ++i) tot += s_wsum[i];
        out[0] = tot / (float)B;
    }
}

extern "C" void kernel_launch(void* const* d_in, const int* in_sizes, int n_in,
                              void* d_out, int out_size, void* d_ws, size_t ws_size,
                              hipStream_t stream)
{
    const float* x     = (const float*)d_in[0];
    const int*   tgt   = (const int*)d_in[1];
    const int*   epoch = (const int*)d_in[2];
    int B = in_sizes[1];
    int C = in_sizes[0] / B;

    unsigned* ceu   = (unsigned*)d_ws;
    unsigned* ghist = ceu + B;              // 16*256 slice bins + ticket

    (void)hipMemsetAsync(ghist, 0, (NSLICE * 256 + 1) * sizeof(unsigned), stream);
    sploss_fused<<<CE_BLOCKS, CE_T, 0, stream>>>(x, tgt, epoch,
                                                 (float*)d_out, ceu, ghist, B, C);
}

// Round 7
// 211.126 us; speedup vs baseline: 1.5947x; 1.5947x over previous
//
#include <hip/hip_runtime.h>
#include <math.h>

// SPLoss, 2-kernel v2 (round 7).
// Round-6 lesson: fused one-kernel tail (256 thr, global re-reads) cost
// ~150 us on one CU (kernel 203 us, occupancy 17.6%, 327 GB/s). The LDS
// stage + 1024-thread tail is mandatory. Keep the fusion's good half:
// CE builds the pass-0 histogram in-register -> LDS -> 16 ghist slices
// (no separate histogram pass over ceu at all).
//  K1 ce_hist_kernel (1024 x 256, 4KB LDS, grid-stride 8 rows/wave):
//     fused CE + per-wave LDS hist + slice merge.
//  K2 select_kernel (1 x 1024, 129KB LDS): stage ceu->LDS (uint4),
//     sum slices, pass-0 scan, radix passes 1-3 from LDS, reweight+mean.
//     Kernel boundary = coherence point: no ticket, plain loads.
// Round-2/3/6 window model: ~152 us = 2x 524MB harness poison fills @87%
// write roofline (not controllable); our slice = K1 (~50 us: 131MB read,
// half L3-hit, competing with fill drain) + K2 (~10 us).
// B=32768, C=1000, fp32.
// ws: [0..B) uint ce bits, [B..B+16*256) slice hists.

__device__ __forceinline__ unsigned f2u(float f) {
    unsigned u = __float_as_uint(f);
    return (u & 0x80000000u) ? ~u : (u | 0x80000000u);
}
__device__ __forceinline__ float u2f(unsigned u) {
    unsigned b = (u & 0x80000000u) ? (u & 0x7FFFFFFFu) : ~u;
    return __uint_as_float(b);
}

#define CE_BLOCKS 1024
#define CE_T      256
#define CE_W      4            // waves per block
#define NSLICE    16

__global__ __launch_bounds__(CE_T) void ce_hist_kernel(
        const float* __restrict__ x, const int* __restrict__ tgt,
        unsigned* __restrict__ ceu, unsigned* __restrict__ ghist, int B, int C)
{
    __shared__ unsigned wh[CE_W][256];    // 4 KB per-wave pass-0 hists

    const int tid  = threadIdx.x;
    const int lane = tid & 63;
    const int wave = tid >> 6;

    #pragma unroll
    for (int j = 0; j < 4; ++j) ((unsigned*)wh)[tid * 4 + j] = 0u;
    __syncthreads();

    const int wstride = CE_BLOCKS * CE_W;              // 4096 waves
    const int C4 = C >> 2;                             // 250 (C%4==0)
    const float NEG = -INFINITY;

    for (int row = blockIdx.x * CE_W + wave; row < B; row += wstride) {
        const float* rp = x + (size_t)row * C;
        const int t = tgt[row];            // dependent pair issued early
        const float tv = rp[t];            // wave-uniform address: 1 transaction

        const float4* p4 = (const float4*)rp;  // row stride 4000 B: 16-B aligned
        float4 v0 = make_float4(NEG, NEG, NEG, NEG), v1 = v0, v2 = v0, v3 = v0;
        if (lane       < C4) v0 = p4[lane];
        if (lane +  64 < C4) v1 = p4[lane + 64];
        if (lane + 128 < C4) v2 = p4[lane + 128];
        if (lane + 192 < C4) v3 = p4[lane + 192];

        float m = fmaxf(fmaxf(fmaxf(v0.x, v0.y), fmaxf(v0.z, v0.w)),
                        fmaxf(fmaxf(v1.x, v1.y), fmaxf(v1.z, v1.w)));
        m = fmaxf(m, fmaxf(fmaxf(v2.x, v2.y), fmaxf(v2.z, v2.w)));
        m = fmaxf(m, fmaxf(fmaxf(v3.x, v3.y), fmaxf(v3.z, v3.w)));
        for (int off = 32; off > 0; off >>= 1)
            m = fmaxf(m, __shfl_xor(m, off, 64));

        float s = __expf(v0.x - m) + __expf(v0.y - m) + __expf(v0.z - m) + __expf(v0.w - m)
                + __expf(v1.x - m) + __expf(v1.y - m) + __expf(v1.z - m) + __expf(v1.w - m)
                + __expf(v2.x - m) + __expf(v2.y - m) + __expf(v2.z - m) + __expf(v2.w - m)
                + __expf(v3.x - m) + __expf(v3.y - m) + __expf(v3.z - m) + __expf(v3.w - m);
        for (int off = 32; off > 0; off >>= 1)
            s += __shfl_xor(s, off, 64);

        if (lane == 0) {
            unsigned cb = f2u((m + __logf(s)) - tv);
            ceu[row] = cb;
            atomicAdd(&wh[wave][cb >> 24], 1u);   // LDS, wave-private hist
        }
    }
    __syncthreads();

    // merge block hist into one of 16 global slices (64 sources/slice)
    if (tid < 256) {
        unsigned s = wh[0][tid] + wh[1][tid] + wh[2][tid] + wh[3][tid];
        if (s) atomicAdd(&ghist[(blockIdx.x & (NSLICE - 1)) * 256 + tid], s);
    }
}

#define T2_T 1024
#define T2_W (T2_T / 64)       // 16 waves

__global__ __launch_bounds__(T2_T) void select_kernel(
        const unsigned* __restrict__ ceu, const unsigned* __restrict__ ghist,
        const int* __restrict__ epoch_p, float* __restrict__ out, int B)
{
    __shared__ unsigned sv[32768];        // 128 KB value stage
    __shared__ unsigned sh[256];
    __shared__ unsigned s_prefix, s_k;
    __shared__ float    s_wsum[T2_W];

    const int tid  = threadIdx.x;
    const int lane = tid & 63;
    const int wave = tid >> 6;

    // ---- stage ceu -> LDS (uint4, 8 iters) ----
    const int n4 = B >> 2;
    for (int i = tid; i < n4; i += T2_T) ((uint4*)sv)[i] = ((const uint4*)ceu)[i];

    // ---- sum 16 ghist slices -> sh (kernel boundary = coherent) ----
    if (tid < 256) {
        unsigned s = 0;
        #pragma unroll
        for (int i = 0; i < NSLICE; ++i) s += ghist[i * 256 + tid];
        sh[tid] = s;
    }
    __syncthreads();

    // schedule (mirrors _adjust_N_ratio_q_t; epoch read on-device)
    const int e = epoch_p[0];
    double nr; int qt;
    if (e <= 25)      { nr = 0.7; qt = 2; }
    else if (e <= 75) { nr = 0.8; qt = 0; }
    else if (e <= 95) { nr = 0.9; qt = 0; }
    else              { nr = 1.0; qt = 0; }
    const bool inv = (qt != 2);           // exponent 1/(qt-1) in {+1,-1}

    // ---- pass 0: bucket find from sh (wave 0) ----
    if (wave == 0) {
        long long kk = (long long)((double)B * nr);          // Python int()
        if (kk > (long long)B - 1) kk = (long long)B - 1;    // jnp index clamp
        unsigned c0 = sh[4 * lane],     c1 = sh[4 * lane + 1];
        unsigned c2 = sh[4 * lane + 2], c3 = sh[4 * lane + 3];
        unsigned cw = c0 + c1 + c2 + c3;
        unsigned incl = cw;
        for (int off = 1; off < 64; off <<= 1) {
            unsigned t = __shfl_up(incl, off, 64);
            if (lane >= off) incl += t;
        }
        unsigned excl = incl - cw;
        unsigned kr = (unsigned)kk;
        unsigned long long bm = __ballot(excl <= kr && kr < excl + cw);
        int L = (int)(__ffsll((long long)bm) - 1);
        if (lane == L) {
            unsigned rem = kr - excl;
            int b; unsigned cum;
            if      (rem < c0)           { b = 0; cum = 0; }
            else if (rem < c0 + c1)      { b = 1; cum = c0; }
            else if (rem < c0 + c1 + c2) { b = 2; cum = c0 + c1; }
            else                         { b = 3; cum = c0 + c1 + c2; }
            s_k = rem - cum;
            s_prefix = (unsigned)(4 * L + b) << 24;
        }
    }
    __syncthreads();

    // ---- passes 1-3 from LDS (spread mantissa bins -> cheap atomics) ----
    for (int p = 1; p < 4; ++p) {
        if (tid < 256) sh[tid] = 0u;
        __syncthreads();
        const int shift = 24 - 8 * p;
        const unsigned hm   = 0xFFFFFFFFu << (shift + 8);
        const unsigned pref = s_prefix;
        for (int j = tid; j < B; j += T2_T) {
            unsigned u = sv[j];
            if ((u & hm) == (pref & hm))
                atomicAdd(&sh[(u >> shift) & 255u], 1u);
        }
        __syncthreads();
        if (wave == 0) {
            unsigned c0 = sh[4 * lane], c1 = sh[4 * lane + 1];
            unsigned c2 = sh[4 * lane + 2], c3 = sh[4 * lane + 3];
            unsigned cw = c0 + c1 + c2 + c3;
            unsigned incl = cw;
            for (int off = 1; off < 64; off <<= 1) {
                unsigned t = __shfl_up(incl, off, 64);
                if (lane >= off) incl += t;
            }
            unsigned excl = incl - cw;
            unsigned kr = s_k;
            unsigned long long bm = __ballot(excl <= kr && kr < excl + cw);
            int L = (int)(__ffsll((long long)bm) - 1);
            if (lane == L) {
                unsigned rem = kr - excl;
                int b; unsigned cum;
                if      (rem < c0)           { b = 0; cum = 0; }
                else if (rem < c0 + c1)      { b = 1; cum = c0; }
                else if (rem < c0 + c1 + c2) { b = 2; cum = c0 + c1; }
                else                         { b = 3; cum = c0 + c1 + c2; }
                s_k = rem - cum;
                s_prefix = pref | ((unsigned)(4 * lane + b) << shift);
            }
        }
        __syncthreads();
    }

    // ---- reweight + mean from LDS ----
    const float lam = u2f(s_prefix);      // exact k-th smallest ce
    float part = 0.0f;
    for (int j = tid; j < B; j += T2_T) {
        float c = u2f(sv[j]);
        float base = 1.0f - c / lam;
        float v = inv ? (1.0f / base) : base;
        if (c >= lam)       v = 0.0f;
        else if (v >= 10.f) v = 10.0f;
        part += c * v;
    }
    for (int off = 32; off > 0; off >>= 1) part += __shfl_xor(part, off, 64);
    if (lane == 0) s_wsum[wave] = part;
    __syncthreads();
    if (tid == 0) {
        float tot = 0.0f;
        for (int i = 0; i < T2_W; ++i) tot += s_wsum[i];
        out[0] = tot / (float)B;
    }
}

extern "C" void kernel_launch(void* const* d_in, const int* in_sizes, int n_in,
                              void* d_out, int out_size, void* d_ws, size_t ws_size,
                              hipStream_t stream)
{
    const float* x     = (const float*)d_in[0];
    const int*   tgt   = (const int*)d_in[1];
    const int*   epoch = (const int*)d_in[2];
    int B = in_sizes[1];
    int C = in_sizes[0] / B;

    unsigned* ceu   = (unsigned*)d_ws;
    unsigned* ghist = ceu + B;              // 16*256 slice bins

    (void)hipMemsetAsync(ghist, 0, NSLICE * 256 * sizeof(unsigned), stream);
    ce_hist_kernel<<<CE_BLOCKS, CE_T, 0, stream>>>(x, tgt, ceu, ghist, B, C);
    select_kernel<<<1, T2_T, 0, stream>>>(ceu, ghist, epoch, (float*)d_out, B);
}